// Round 6
// baseline (243.409 us; speedup 1.0000x reference)
//
#include <hip/hip_runtime.h>
#include <hip/hip_bf16.h>

#define NN 4096
#define FD 128
#define NDIM 2

// ---------- workspace layout (float offsets) ----------
// hmat [2][3][4096][128] fp32 : q=0 X@Ws (h_s), q=1 X@Wu, q=2 X@Wd
// svec [2][4][4096]           : v=0 s1u, 1 s2u, 2 s1d, 3 s2d
// hp   [2][4][4096][128] fp32 : split-K partials of L@h0
// gu,gd [2][4096][128]
// h0T/huT/hdT [2][128][4096] f16 : transposed f16 copies (MFMA B operands)
#define OFF_HMAT 0
#define OFF_SVEC 3145728
#define OFF_HP   3178496
#define OFF_GU   7372800
#define OFF_GD   8421376
#define OFF_H0T  9469952
#define OFF_HUT  9994240
#define OFF_HDT  10518528

typedef _Float16 f16x8 __attribute__((ext_vector_type(8)));
typedef float f32x4 __attribute__((ext_vector_type(4)));

union P4 { _Float16 h[4]; int2 i2; };

__device__ __forceinline__ float f4get(const float4& v, int j) {
    return j == 0 ? v.x : j == 1 ? v.y : j == 2 ? v.z : v.w;
}

// ---------------- K1: MFMA f16 GEMM  h = X @ W_p, tile 128x128, K=128 ----------------
// p==0 -> h0T f16 transposed only; p==1 -> hmat q0; p==2/3 -> hmat q1/q2 + huT/hdT
__global__ __launch_bounds__(256) void k_xw(
    const float* __restrict__ X, const float* __restrict__ Wp,
    const float* __restrict__ Wsm, const float* __restrict__ Wu,
    const float* __restrict__ Wd, float* __restrict__ hmat,
    _Float16* __restrict__ h0T, _Float16* __restrict__ huT,
    _Float16* __restrict__ hdT) {
  int d = blockIdx.z, p = blockIdx.y;
  int r0 = blockIdx.x * 128;
  const float* W = (p == 0 ? Wp : p == 1 ? Wsm : p == 2 ? Wu : Wd) + (size_t)d * FD * FD;
  const float* Xd = X + ((size_t)d * NN + r0) * FD;
  __shared__ int4 As4[2048];  // 32 KB
  __shared__ int4 Bs4[2048];  // 32 KB
  char* As = (char*)As4; char* Bs = (char*)Bs4;
  int t = threadIdx.x;

#pragma unroll 4
  for (int u = 0; u < 16; u++) {
    int id = t + u * 256;
    int row = id >> 5, k4 = (id & 31) * 4;
    float4 v = *(const float4*)(Xd + (size_t)row * FD + k4);
    P4 pk;
    pk.h[0] = (_Float16)v.x; pk.h[1] = (_Float16)v.y;
    pk.h[2] = (_Float16)v.z; pk.h[3] = (_Float16)v.w;
    int off = (row * 256 + k4 * 2) ^ ((row & 7) << 4);
    *(int2*)(As + off) = pk.i2;
  }
#pragma unroll 4
  for (int u = 0; u < 16; u++) {
    int id = t + u * 256;
    int k = id >> 5, n4 = (id & 31) * 4;
    float4 v = *(const float4*)(W + (size_t)k * FD + n4);
#pragma unroll
    for (int j = 0; j < 4; j++) {
      int n = n4 + j;
      int off = (n * 256 + k * 2) ^ ((n & 7) << 4);
      *(_Float16*)(Bs + off) = (_Float16)f4get(v, j);
    }
  }
  __syncthreads();

  int w = t >> 6, l = t & 63;
  int lr = l & 15, lkb = (l >> 4) * 16;
  f32x4 acc[2][8] = {};
#pragma unroll
  for (int kb = 0; kb < 4; kb++) {
    f16x8 a[2], b[8];
#pragma unroll
    for (int m = 0; m < 2; m++) {
      int row = w * 32 + m * 16 + lr;
      int off = (row * 256 + kb * 64 + lkb) ^ ((row & 7) << 4);
      a[m] = *(const f16x8*)(As + off);
    }
#pragma unroll
    for (int n = 0; n < 8; n++) {
      int rn = n * 16 + lr;
      int off = (rn * 256 + kb * 64 + lkb) ^ ((rn & 7) << 4);
      b[n] = *(const f16x8*)(Bs + off);
    }
#pragma unroll
    for (int m = 0; m < 2; m++)
#pragma unroll
      for (int n = 0; n < 8; n++)
        acc[m][n] = __builtin_amdgcn_mfma_f32_16x16x32_f16(a[m], b[n], acc[m][n], 0, 0, 0);
  }

  if (p != 1) {
    _Float16* hT = (p == 0 ? h0T : p == 2 ? huT : hdT) + (size_t)d * FD * NN;
#pragma unroll
    for (int m = 0; m < 2; m++)
#pragma unroll
      for (int n = 0; n < 8; n++) {
        int col = n * 16 + lr;
        int grow = r0 + w * 32 + m * 16 + (l >> 4) * 4;
        P4 pk;
#pragma unroll
        for (int r = 0; r < 4; r++) pk.h[r] = (_Float16)acc[m][n][r];
        *(int2*)(hT + (size_t)col * NN + grow) = pk.i2;
      }
  }
  if (p != 0) {
    float* o = hmat + ((size_t)(d * 3 + p - 1) * NN + r0) * FD;
#pragma unroll
    for (int m = 0; m < 2; m++)
#pragma unroll
      for (int n = 0; n < 8; n++)
#pragma unroll
        for (int r = 0; r < 4; r++)
          o[(size_t)(w * 32 + m * 16 + (l >> 4) * 4 + r) * FD + n * 16 + lr] = acc[m][n][r];
  }
}

// ---------------- K1b: svec = h @ a ----------------
__global__ __launch_bounds__(256) void k_svec(
    const float* __restrict__ hmat, const float* __restrict__ au1,
    const float* __restrict__ au2, const float* __restrict__ ad1,
    const float* __restrict__ ad2, float* __restrict__ svec) {
  int v = blockIdx.y, d = blockIdx.z;
  int w = threadIdx.x >> 6, lane = threadIdx.x & 63;
  int i = blockIdx.x * 4 + w;
  const float* a = (v == 0 ? au1 : v == 1 ? au2 : v == 2 ? ad1 : ad2) + (size_t)d * FD;
  const float* h = hmat + ((size_t)(d * 3 + 1 + (v >> 1)) * NN + i) * FD;
  float x = h[lane] * a[lane] + h[64 + lane] * a[64 + lane];
#pragma unroll
  for (int o = 1; o < 64; o <<= 1) x += __shfl_xor(x, o);
  if (lane == 0) svec[(size_t)(d * 4 + v) * NN + i] = x;
}

// ---------------- K2: MFMA f16 GEMM  hp[d][ks] = L[d][:,slice] @ h0[slice,:]
//                  BM=64, 512 blocks = 2 blocks/CU (standalone again) ----
__global__ __launch_bounds__(256) void k_lgemm(
    const float* __restrict__ L, const _Float16* __restrict__ h0T,
    float* __restrict__ hp) {
  int d = blockIdx.z, ks = blockIdx.y;
  int r0 = blockIdx.x * 64;
  const float* Lr = L + (size_t)d * NN * NN;
  const _Float16* hT = h0T + (size_t)d * FD * NN;
  __shared__ int4 As4[512];   //  8 KB
  __shared__ int4 Bs4[1024];  // 16 KB
  char* As = (char*)As4; char* Bs = (char*)Bs4;
  int t = threadIdx.x;
  int w = t >> 6, l = t & 63;
  int lr = l & 15, lkb = (l >> 4) * 16;
  f32x4 acc[8] = {};
  int kbeg = ks * 1024;
  for (int kk = kbeg; kk < kbeg + 1024; kk += 64) {
#pragma unroll
    for (int u = 0; u < 4; u++) {
      int id = t + u * 256;
      int row = id >> 4, k4 = (id & 15) * 4;
      float4 v = *(const float4*)(Lr + (size_t)(r0 + row) * NN + kk + k4);
      P4 pk;
      pk.h[0] = (_Float16)v.x; pk.h[1] = (_Float16)v.y;
      pk.h[2] = (_Float16)v.z; pk.h[3] = (_Float16)v.w;
      int off = (row * 128 + k4 * 2) ^ ((row & 7) << 4);
      *(int2*)(As + off) = pk.i2;
    }
#pragma unroll
    for (int u = 0; u < 4; u++) {
      int id = t + u * 256;
      int n = id >> 3, k8 = (id & 7) * 8;
      int4 v = *(const int4*)(hT + (size_t)n * NN + kk + k8);
      int off = (n * 128 + k8 * 2) ^ ((n & 7) << 4);
      *(int4*)(Bs + off) = v;
    }
    __syncthreads();
#pragma unroll
    for (int kb = 0; kb < 2; kb++) {
      int row = w * 16 + lr;
      int offA = (row * 128 + kb * 64 + lkb) ^ ((row & 7) << 4);
      f16x8 a = *(const f16x8*)(As + offA);
      f16x8 b[8];
#pragma unroll
      for (int n = 0; n < 8; n++) {
        int rn = n * 16 + lr;
        int off = (rn * 128 + kb * 64 + lkb) ^ ((rn & 7) << 4);
        b[n] = *(const f16x8*)(Bs + off);
      }
#pragma unroll
      for (int n = 0; n < 8; n++)
        acc[n] = __builtin_amdgcn_mfma_f32_16x16x32_f16(a, b[n], acc[n], 0, 0, 0);
    }
    __syncthreads();
  }
  float* o = hp + ((size_t)(d * 4 + ks) * NN + r0) * FD;
#pragma unroll
  for (int n = 0; n < 8; n++)
#pragma unroll
    for (int r = 0; r < 4; r++)
      o[(size_t)(w * 16 + (l >> 4) * 4 + r) * FD + n * 16 + lr] = acc[n][r];
}

// ---------------- K3: flash-GAT — dense masked-softmax GEMM via MFMA -------
// One block = 32 output rows x 128 cols for one (d, adj). K = 4096 in BK=64.
// P = adj * exp(leaky(s1_i + s2_j)) formed in regs -> f16 LDS (A operand).
// num = P @ h (MFMA), den = P @ ones (MFMA). out = num/den (0 if den==0).
__global__ __launch_bounds__(256) void k_fgat(
    const float* __restrict__ Lu, const float* __restrict__ Ldn,
    const _Float16* __restrict__ huT, const _Float16* __restrict__ hdT,
    const float* __restrict__ svec,
    float* __restrict__ gu, float* __restrict__ gd) {
  int r0 = blockIdx.x * 32;
  int a = blockIdx.y, d = blockIdx.z;
  const float* A = (a ? Ldn : Lu) + (size_t)d * NN * NN;
  const _Float16* hT = (a ? hdT : huT) + (size_t)d * FD * NN;
  const float* s1 = svec + (size_t)(d * 4 + 2 * a) * NN;
  const float* s2 = svec + (size_t)(d * 4 + 2 * a + 1) * NN;
  float* g = (a ? gd : gu) + ((size_t)d * NN + r0) * FD;

  __shared__ char Ps[32 * 128];    //  4 KB: P [32 rows][64 j] f16, swizzled
  __shared__ char Bs[128 * 128];   // 16 KB: hT [128 col][64 j] f16, swizzled

  int t = threadIdx.x, w = t >> 6, l = t & 63;
  int wm = w >> 1, wn = w & 1;
  int lr = l & 15, lkb = (l >> 4) * 16;

  // staging geometry (constant per thread)
  int row = t >> 4, j4 = (t & 15) * 4;        // P: rows {row, row+16}, 4 j's
  int n0 = t >> 3, k8 = (t & 7) * 8;          // B: cols {n0, n0+32, +64, +96}
  const float* pA0 = A + (size_t)(r0 + row) * NN + j4;
  const float* pA1 = pA0 + (size_t)16 * NN;
  const float* pS = s2 + j4;
  const _Float16* pB0 = hT + (size_t)n0 * NN + k8;
  int offP0 = (row * 128 + j4 * 2) ^ ((row & 7) << 4);
  int offB0 = (n0 * 128 + k8 * 2) ^ ((n0 & 7) << 4);
  float s1a = s1[r0 + row];
  float s1b = s1[r0 + 16 + row];

  f16x8 ones = {(_Float16)1.f, (_Float16)1.f, (_Float16)1.f, (_Float16)1.f,
                (_Float16)1.f, (_Float16)1.f, (_Float16)1.f, (_Float16)1.f};
  f32x4 acc[4] = {};
  f32x4 dacc = {};

  // prologue: load tile 0 into regs
  float4 av0 = *(const float4*)(pA0);
  float4 av1 = *(const float4*)(pA1);
  float4 sv  = *(const float4*)(pS);
  int4 bv[4];
#pragma unroll
  for (int u = 0; u < 4; u++) bv[u] = *(const int4*)(pB0 + (size_t)(32 * u) * NN);

  for (int jb = 0; jb < NN; jb += 64) {
    // ---- stage current tile from regs to LDS ----
    {
      P4 pk0, pk1;
#pragma unroll
      for (int q = 0; q < 4; q++) {
        float sc0 = s1a + f4get(sv, q);
        sc0 = sc0 > 0.f ? sc0 : 0.01f * sc0;
        pk0.h[q] = (_Float16)((f4get(av0, q) == 1.0f) ? __expf(sc0) : 0.0f);
        float sc1 = s1b + f4get(sv, q);
        sc1 = sc1 > 0.f ? sc1 : 0.01f * sc1;
        pk1.h[q] = (_Float16)((f4get(av1, q) == 1.0f) ? __expf(sc1) : 0.0f);
      }
      *(int2*)(Ps + offP0) = pk0.i2;
      *(int2*)(Ps + offP0 + 2048) = pk1.i2;
#pragma unroll
      for (int u = 0; u < 4; u++) *(int4*)(Bs + offB0 + u * 4096) = bv[u];
    }
    // ---- issue next tile's loads (overlap with MFMA below) ----
    if (jb + 64 < NN) {
      av0 = *(const float4*)(pA0 + jb + 64);
      av1 = *(const float4*)(pA1 + jb + 64);
      sv  = *(const float4*)(pS + jb + 64);
#pragma unroll
      for (int u = 0; u < 4; u++)
        bv[u] = *(const int4*)(pB0 + (size_t)(32 * u) * NN + jb + 64);
    }
    __syncthreads();
#pragma unroll
    for (int kb = 0; kb < 2; kb++) {
      int prow = wm * 16 + lr;
      int offA = (prow * 128 + kb * 64 + lkb) ^ ((prow & 7) << 4);
      f16x8 pa = *(const f16x8*)(Ps + offA);
      dacc = __builtin_amdgcn_mfma_f32_16x16x32_f16(pa, ones, dacc, 0, 0, 0);
#pragma unroll
      for (int n = 0; n < 4; n++) {
        int col = wn * 64 + n * 16 + lr;
        int offB = (col * 128 + kb * 64 + lkb) ^ ((col & 7) << 4);
        f16x8 bb = *(const f16x8*)(Bs + offB);
        acc[n] = __builtin_amdgcn_mfma_f32_16x16x32_f16(pa, bb, acc[n], 0, 0, 0);
      }
    }
    __syncthreads();
  }

  // epilogue: row = wm*16 + (l>>4)*4 + r (D layout), den replicated over cols
#pragma unroll
  for (int r = 0; r < 4; r++) {
    int orow = wm * 16 + (l >> 4) * 4 + r;
    float den = dacc[r];
    float inv = den > 0.0f ? 1.0f / den : 0.0f;
#pragma unroll
    for (int n = 0; n < 4; n++)
      g[(size_t)orow * FD + wn * 64 + n * 16 + lr] = acc[n][r] * inv;
  }
}

// ---------------- K4: combine with tanh ----------------
__global__ __launch_bounds__(256) void k_combine(
    const float* __restrict__ hmat, const float* __restrict__ hp,
    const float* __restrict__ gu, const float* __restrict__ gd,
    float* __restrict__ out) {
  const size_t tot4 = (size_t)NDIM * NN * FD / 4;
  for (size_t i4 = (size_t)blockIdx.x * blockDim.x + threadIdx.x; i4 < tot4;
       i4 += (size_t)gridDim.x * blockDim.x) {
    size_t i = i4 * 4;
    int d = (int)(i >> 19);
    size_t rem = i & 524287;
    float4 hs = *(const float4*)(hmat + ((size_t)(d * 3) << 19) + rem);
    float4 p0 = *(const float4*)(hp + ((size_t)(d * 4 + 0) << 19) + rem);
    float4 p1 = *(const float4*)(hp + ((size_t)(d * 4 + 1) << 19) + rem);
    float4 p2 = *(const float4*)(hp + ((size_t)(d * 4 + 2) << 19) + rem);
    float4 p3 = *(const float4*)(hp + ((size_t)(d * 4 + 3) << 19) + rem);
    float4 u = *(const float4*)(gu + ((size_t)d << 19) + rem);
    float4 dd = *(const float4*)(gd + ((size_t)d << 19) + rem);
    float4 o;
    o.x = tanhf(hs.x) + tanhf(u.x) + tanhf(dd.x) + tanhf(p0.x + p1.x + p2.x + p3.x);
    o.y = tanhf(hs.y) + tanhf(u.y) + tanhf(dd.y) + tanhf(p0.y + p1.y + p2.y + p3.y);
    o.z = tanhf(hs.z) + tanhf(u.z) + tanhf(dd.z) + tanhf(p0.z + p1.z + p2.z + p3.z);
    o.w = tanhf(hs.w) + tanhf(u.w) + tanhf(dd.w) + tanhf(p0.w + p1.w + p2.w + p3.w);
    *(float4*)(out + i) = o;
  }
}

extern "C" void kernel_launch(void* const* d_in, const int* in_sizes, int n_in,
                              void* d_out, int out_size, void* d_ws, size_t ws_size,
                              hipStream_t stream) {
  const float* X   = (const float*)d_in[0];
  const float* L   = (const float*)d_in[1];
  const float* Lu  = (const float*)d_in[2];
  const float* Ldn = (const float*)d_in[3];
  const float* Wp  = (const float*)d_in[4];
  const float* Wsm = (const float*)d_in[5];
  const float* Wu  = (const float*)d_in[6];
  const float* au1 = (const float*)d_in[7];
  const float* au2 = (const float*)d_in[8];
  const float* Wd  = (const float*)d_in[9];
  const float* ad1 = (const float*)d_in[10];
  const float* ad2 = (const float*)d_in[11];
  float* out = (float*)d_out;
  float* ws = (float*)d_ws;

  float* hmat = ws + OFF_HMAT;
  float* svec = ws + OFF_SVEC;
  float* hp   = ws + OFF_HP;
  float* gu   = ws + OFF_GU;
  float* gd   = ws + OFF_GD;
  _Float16* h0T = (_Float16*)(ws + OFF_H0T);
  _Float16* huT = (_Float16*)(ws + OFF_HUT);
  _Float16* hdT = (_Float16*)(ws + OFF_HDT);

  k_xw<<<dim3(NN / 128, 4, NDIM), 256, 0, stream>>>(X, Wp, Wsm, Wu, Wd, hmat,
                                                    h0T, huT, hdT);
  k_svec<<<dim3(NN / 4, 4, NDIM), 256, 0, stream>>>(hmat, au1, au2, ad1, ad2, svec);
  k_lgemm<<<dim3(NN / 64, 4, NDIM), 256, 0, stream>>>(L, h0T, hp);
  k_fgat<<<dim3(NN / 32, 2, NDIM), 256, 0, stream>>>(Lu, Ldn, huT, hdT, svec, gu, gd);
  k_combine<<<1024, 256, 0, stream>>>(hmat, hp, gu, gd, out);
}

// Round 7
// 141.796 us; speedup vs baseline: 1.7166x; 1.7166x over previous
//
#include <hip/hip_runtime.h>
#include <hip/hip_bf16.h>

#define NN 4096
#define FD 128
#define NDIM 2
#define CAP 256

typedef unsigned long long u64;

// ---------- workspace layout (float offsets) ----------
// hmat [2][3][4096][128] fp32 : q=0 X@Ws (h_s), q=1 X@Wu, q=2 X@Wd
// svec [2][4][4096]           : v=0 s1u, 1 s2u, 2 s1d, 3 s2d
// hp   [2][4][4096][128] fp32 : split-K partials of L@h0
// gu,gd [2][4096][128]
// h0T  [2][128][4096] f16     : (X@Wp) transposed, f16 (B operand of L-GEMM)
// mask [2][2][4096][64] u64   : bit-packed adjacency (bit l of word w: col=(w>>2)*256+4l+(w&3))
#define OFF_HMAT 0
#define OFF_SVEC 3145728
#define OFF_HP   3178496
#define OFF_GU   7372800
#define OFF_GD   8421376
#define OFF_H0T  9469952
#define OFF_MASK 9994240

typedef _Float16 f16x8 __attribute__((ext_vector_type(8)));
typedef float f32x4 __attribute__((ext_vector_type(4)));

union P4 { _Float16 h[4]; int2 i2; };

__device__ __forceinline__ float f4get(const float4& v, int j) {
    return j == 0 ? v.x : j == 1 ? v.y : j == 2 ? v.z : v.w;
}

// ---------------- K1: MFMA f16 GEMM  h = X @ W_p, tile 128x128, K=128 ----------------
__global__ __launch_bounds__(256) void k_xw(
    const float* __restrict__ X, const float* __restrict__ Wp,
    const float* __restrict__ Wsm, const float* __restrict__ Wu,
    const float* __restrict__ Wd, float* __restrict__ hmat,
    _Float16* __restrict__ h0T) {
  int d = blockIdx.z, p = blockIdx.y;
  int r0 = blockIdx.x * 128;
  const float* W = (p == 0 ? Wp : p == 1 ? Wsm : p == 2 ? Wu : Wd) + (size_t)d * FD * FD;
  const float* Xd = X + ((size_t)d * NN + r0) * FD;
  __shared__ int4 As4[2048];  // 32 KB
  __shared__ int4 Bs4[2048];  // 32 KB
  char* As = (char*)As4; char* Bs = (char*)Bs4;
  int t = threadIdx.x;

#pragma unroll 4
  for (int u = 0; u < 16; u++) {
    int id = t + u * 256;
    int row = id >> 5, k4 = (id & 31) * 4;
    float4 v = *(const float4*)(Xd + (size_t)row * FD + k4);
    P4 pk;
    pk.h[0] = (_Float16)v.x; pk.h[1] = (_Float16)v.y;
    pk.h[2] = (_Float16)v.z; pk.h[3] = (_Float16)v.w;
    int off = (row * 256 + k4 * 2) ^ ((row & 7) << 4);
    *(int2*)(As + off) = pk.i2;
  }
#pragma unroll 4
  for (int u = 0; u < 16; u++) {
    int id = t + u * 256;
    int k = id >> 5, n4 = (id & 31) * 4;
    float4 v = *(const float4*)(W + (size_t)k * FD + n4);
#pragma unroll
    for (int j = 0; j < 4; j++) {
      int n = n4 + j;
      int off = (n * 256 + k * 2) ^ ((n & 7) << 4);
      *(_Float16*)(Bs + off) = (_Float16)f4get(v, j);
    }
  }
  __syncthreads();

  int w = t >> 6, l = t & 63;
  int lr = l & 15, lkb = (l >> 4) * 16;
  f32x4 acc[2][8] = {};
#pragma unroll
  for (int kb = 0; kb < 4; kb++) {
    f16x8 a[2], b[8];
#pragma unroll
    for (int m = 0; m < 2; m++) {
      int row = w * 32 + m * 16 + lr;
      int off = (row * 256 + kb * 64 + lkb) ^ ((row & 7) << 4);
      a[m] = *(const f16x8*)(As + off);
    }
#pragma unroll
    for (int n = 0; n < 8; n++) {
      int rn = n * 16 + lr;
      int off = (rn * 256 + kb * 64 + lkb) ^ ((rn & 7) << 4);
      b[n] = *(const f16x8*)(Bs + off);
    }
#pragma unroll
    for (int m = 0; m < 2; m++)
#pragma unroll
      for (int n = 0; n < 8; n++)
        acc[m][n] = __builtin_amdgcn_mfma_f32_16x16x32_f16(a[m], b[n], acc[m][n], 0, 0, 0);
  }

  if (p == 0) {
    _Float16* hT = h0T + (size_t)d * FD * NN;
#pragma unroll
    for (int m = 0; m < 2; m++)
#pragma unroll
      for (int n = 0; n < 8; n++) {
        int col = n * 16 + lr;
        int grow = r0 + w * 32 + m * 16 + (l >> 4) * 4;
        P4 pk;
#pragma unroll
        for (int r = 0; r < 4; r++) pk.h[r] = (_Float16)acc[m][n][r];
        *(int2*)(hT + (size_t)col * NN + grow) = pk.i2;
      }
  } else {
    float* o = hmat + ((size_t)(d * 3 + p - 1) * NN + r0) * FD;
#pragma unroll
    for (int m = 0; m < 2; m++)
#pragma unroll
      for (int n = 0; n < 8; n++)
#pragma unroll
        for (int r = 0; r < 4; r++)
          o[(size_t)(w * 32 + m * 16 + (l >> 4) * 4 + r) * FD + n * 16 + lr] = acc[m][n][r];
  }
}

// ---------------- K1b: svec = h @ a ----------------
__global__ __launch_bounds__(256) void k_svec(
    const float* __restrict__ hmat, const float* __restrict__ au1,
    const float* __restrict__ au2, const float* __restrict__ ad1,
    const float* __restrict__ ad2, float* __restrict__ svec) {
  int v = blockIdx.y, d = blockIdx.z;
  int w = threadIdx.x >> 6, lane = threadIdx.x & 63;
  int i = blockIdx.x * 4 + w;
  const float* a = (v == 0 ? au1 : v == 1 ? au2 : v == 2 ? ad1 : ad2) + (size_t)d * FD;
  const float* h = hmat + ((size_t)(d * 3 + 1 + (v >> 1)) * NN + i) * FD;
  float x = h[lane] * a[lane] + h[64 + lane] * a[64 + lane];
#pragma unroll
  for (int o = 1; o < 64; o <<= 1) x += __shfl_xor(x, o);
  if (lane == 0) svec[(size_t)(d * 4 + v) * NN + i] = x;
}

// ---------------- K2: MFMA f16 GEMM  hp[d][ks] = L[d][:,slice] @ h0[slice,:] ----
__global__ __launch_bounds__(256) void k_lgemm(
    const float* __restrict__ L, const _Float16* __restrict__ h0T,
    float* __restrict__ hp) {
  int d = blockIdx.z, ks = blockIdx.y;
  int r0 = blockIdx.x * 64;
  const float* Lr = L + (size_t)d * NN * NN;
  const _Float16* hT = h0T + (size_t)d * FD * NN;
  __shared__ int4 As4[512];   //  8 KB
  __shared__ int4 Bs4[1024];  // 16 KB
  char* As = (char*)As4; char* Bs = (char*)Bs4;
  int t = threadIdx.x;
  int w = t >> 6, l = t & 63;
  int lr = l & 15, lkb = (l >> 4) * 16;
  f32x4 acc[8] = {};
  int kbeg = ks * 1024;
  for (int kk = kbeg; kk < kbeg + 1024; kk += 64) {
#pragma unroll
    for (int u = 0; u < 4; u++) {
      int id = t + u * 256;
      int row = id >> 4, k4 = (id & 15) * 4;
      float4 v = *(const float4*)(Lr + (size_t)(r0 + row) * NN + kk + k4);
      P4 pk;
      pk.h[0] = (_Float16)v.x; pk.h[1] = (_Float16)v.y;
      pk.h[2] = (_Float16)v.z; pk.h[3] = (_Float16)v.w;
      int off = (row * 128 + k4 * 2) ^ ((row & 7) << 4);
      *(int2*)(As + off) = pk.i2;
    }
#pragma unroll
    for (int u = 0; u < 4; u++) {
      int id = t + u * 256;
      int n = id >> 3, k8 = (id & 7) * 8;
      int4 v = *(const int4*)(hT + (size_t)n * NN + kk + k8);
      int off = (n * 128 + k8 * 2) ^ ((n & 7) << 4);
      *(int4*)(Bs + off) = v;
    }
    __syncthreads();
#pragma unroll
    for (int kb = 0; kb < 2; kb++) {
      int row = w * 16 + lr;
      int offA = (row * 128 + kb * 64 + lkb) ^ ((row & 7) << 4);
      f16x8 a = *(const f16x8*)(As + offA);
      f16x8 b[8];
#pragma unroll
      for (int n = 0; n < 8; n++) {
        int rn = n * 16 + lr;
        int off = (rn * 128 + kb * 64 + lkb) ^ ((rn & 7) << 4);
        b[n] = *(const f16x8*)(Bs + off);
      }
#pragma unroll
      for (int n = 0; n < 8; n++)
        acc[n] = __builtin_amdgcn_mfma_f32_16x16x32_f16(a, b[n], acc[n], 0, 0, 0);
    }
    __syncthreads();
  }
  float* o = hp + ((size_t)(d * 4 + ks) * NN + r0) * FD;
#pragma unroll
  for (int n = 0; n < 8; n++)
#pragma unroll
    for (int r = 0; r < 4; r++)
      o[(size_t)(w * 16 + (l >> 4) * 4 + r) * FD + n * 16 + lr] = acc[n][r];
}

// ---------------- K3a: bit-pack adjacency (pure streaming) ----------------
// Pair = 512 consecutive cols of one row of one plane. Wave loads 2x1KB,
// 8 ballots, lane0 stores 8 u64. Word w (0..63) of a row: bit l -> col
// (w>>2)*256 + 4*l + (w&3).
__global__ __launch_bounds__(256) void k_pack(
    const float* __restrict__ Lu, const float* __restrict__ Ldn,
    u64* __restrict__ mask) {
  int lane = threadIdx.x & 63;
  int wid = (blockIdx.x * 256 + threadIdx.x) >> 6;
  int nw = (gridDim.x * 256) >> 6;
  const int TOT = 4 * NN * 8;  // 131072 pairs
  for (int pair = wid; pair < TOT; pair += nw) {
    int p = pair >> 15;           // plane: d = p>>1, a = p&1
    int rg = pair & 32767;
    int row = rg >> 3, g2 = rg & 7;
    const float* src = ((p & 1) ? Ldn : Lu) +
                       ((size_t)(p >> 1) * NN + row) * (size_t)NN + g2 * 512;
    float4 v0 = *(const float4*)(src + 4 * lane);
    float4 v1 = *(const float4*)(src + 256 + 4 * lane);
    u64 m0 = __ballot(v0.x == 1.0f);
    u64 m1 = __ballot(v0.y == 1.0f);
    u64 m2 = __ballot(v0.z == 1.0f);
    u64 m3 = __ballot(v0.w == 1.0f);
    u64 m4 = __ballot(v1.x == 1.0f);
    u64 m5 = __ballot(v1.y == 1.0f);
    u64 m6 = __ballot(v1.z == 1.0f);
    u64 m7 = __ballot(v1.w == 1.0f);
    if (lane == 0) {
      u64* o = mask + ((size_t)p * NN + row) * 64 + g2 * 8;
      ulonglong2 a0 = {m0, m1}, a1 = {m2, m3}, a2 = {m4, m5}, a3 = {m6, m7};
      *(ulonglong2*)(o + 0) = a0;
      *(ulonglong2*)(o + 2) = a1;
      *(ulonglong2*)(o + 4) = a2;
      *(ulonglong2*)(o + 6) = a3;
    }
  }
}

// ---------------- K3b: GAT from bitmask (wave per row) ----------------
__global__ __launch_bounds__(256) void k_gat2(
    const u64* __restrict__ mask, const float* __restrict__ hmat,
    const float* __restrict__ svec, float* __restrict__ gu,
    float* __restrict__ gd) {
  int d = blockIdx.z, a = blockIdx.y;
  int w = threadIdx.x >> 6, lane = threadIdx.x & 63;
  int i = blockIdx.x * 4 + w;
  const u64* mrow = mask + ((size_t)((d * 2 + a) * NN) + i) * 64;
  const float* h = hmat + (size_t)(d * 3 + 1 + a) * NN * FD;
  const float* s1 = svec + (size_t)(d * 4 + 2 * a) * NN;
  const float* s2 = svec + (size_t)(d * 4 + 2 * a + 1) * NN;
  float* g = (a ? gd : gu) + ((size_t)d * NN + i) * FD;

  __shared__ int ej[4][CAP];
  __shared__ float wt[4][CAP];

  // --- decode: lane l owns word l; prefix-sum counts; extract bits ---
  u64 m = mrow[lane];
  int c = __popcll(m);
  int pre = c;
#pragma unroll
  for (int o = 1; o < 64; o <<= 1) {
    int tv = __shfl_up(pre, o);
    if (lane >= o) pre += tv;
  }
  int cnt = __shfl(pre, 63);
  int base = pre - c;
  int colbase = (lane >> 2) * 256 + (lane & 3);
  while (m) {
    int b = __ffsll((unsigned long long)m) - 1;
    m &= m - 1;
    if (base < CAP) ej[w][base] = colbase + b * 4;
    base++;
  }
  cnt = min(cnt, CAP);

  // --- softmax over edges ---
  float s1i = s1[i];
  float mx = -1e30f;
  for (int e0 = 0; e0 < cnt; e0 += 64) {
    int e = e0 + lane;
    float sc = -1e30f;
    if (e < cnt) {
      int j = ej[w][e];
      float x = s1i + s2[j];
      sc = x > 0.0f ? x : 0.01f * x;
      wt[w][e] = sc;
    }
    mx = fmaxf(mx, sc);
  }
#pragma unroll
  for (int o = 1; o < 64; o <<= 1) mx = fmaxf(mx, __shfl_xor(mx, o));
  float sum = 0.0f;
  for (int e0 = 0; e0 < cnt; e0 += 64) {
    int e = e0 + lane;
    float pv = 0.0f;
    if (e < cnt) {
      pv = expf(wt[w][e] - mx);
      wt[w][e] = pv;
    }
    sum += pv;
  }
#pragma unroll
  for (int o = 1; o < 64; o <<= 1) sum += __shfl_xor(sum, o);
  float inv = (cnt > 0) ? 1.0f / sum : 0.0f;

  // --- gather: 4 edges (8 independent 256B loads) in flight ---
  float acc0 = 0.0f, acc1 = 0.0f;
  int e = 0;
  for (; e + 4 <= cnt; e += 4) {
    const float* r0 = h + (size_t)ej[w][e + 0] * FD;
    const float* r1 = h + (size_t)ej[w][e + 1] * FD;
    const float* r2 = h + (size_t)ej[w][e + 2] * FD;
    const float* r3 = h + (size_t)ej[w][e + 3] * FD;
    float w0 = wt[w][e + 0] * inv, w1 = wt[w][e + 1] * inv;
    float w2 = wt[w][e + 2] * inv, w3 = wt[w][e + 3] * inv;
    float a0 = r0[lane], b0 = r0[64 + lane];
    float a1 = r1[lane], b1 = r1[64 + lane];
    float a2 = r2[lane], b2 = r2[64 + lane];
    float a3 = r3[lane], b3 = r3[64 + lane];
    acc0 += w0 * a0 + w1 * a1 + w2 * a2 + w3 * a3;
    acc1 += w0 * b0 + w1 * b1 + w2 * b2 + w3 * b3;
  }
  for (; e < cnt; e++) {
    float wg = wt[w][e] * inv;
    const float* hr = h + (size_t)ej[w][e] * FD;
    acc0 += wg * hr[lane];
    acc1 += wg * hr[64 + lane];
  }
  g[lane] = acc0;
  g[64 + lane] = acc1;
}

// ---------------- K4: combine with tanh ----------------
__global__ __launch_bounds__(256) void k_combine(
    const float* __restrict__ hmat, const float* __restrict__ hp,
    const float* __restrict__ gu, const float* __restrict__ gd,
    float* __restrict__ out) {
  const size_t tot4 = (size_t)NDIM * NN * FD / 4;
  for (size_t i4 = (size_t)blockIdx.x * blockDim.x + threadIdx.x; i4 < tot4;
       i4 += (size_t)gridDim.x * blockDim.x) {
    size_t i = i4 * 4;
    int d = (int)(i >> 19);
    size_t rem = i & 524287;
    float4 hs = *(const float4*)(hmat + ((size_t)(d * 3) << 19) + rem);
    float4 p0 = *(const float4*)(hp + ((size_t)(d * 4 + 0) << 19) + rem);
    float4 p1 = *(const float4*)(hp + ((size_t)(d * 4 + 1) << 19) + rem);
    float4 p2 = *(const float4*)(hp + ((size_t)(d * 4 + 2) << 19) + rem);
    float4 p3 = *(const float4*)(hp + ((size_t)(d * 4 + 3) << 19) + rem);
    float4 u = *(const float4*)(gu + ((size_t)d << 19) + rem);
    float4 dd = *(const float4*)(gd + ((size_t)d << 19) + rem);
    float4 o;
    o.x = tanhf(hs.x) + tanhf(u.x) + tanhf(dd.x) + tanhf(p0.x + p1.x + p2.x + p3.x);
    o.y = tanhf(hs.y) + tanhf(u.y) + tanhf(dd.y) + tanhf(p0.y + p1.y + p2.y + p3.y);
    o.z = tanhf(hs.z) + tanhf(u.z) + tanhf(dd.z) + tanhf(p0.z + p1.z + p2.z + p3.z);
    o.w = tanhf(hs.w) + tanhf(u.w) + tanhf(dd.w) + tanhf(p0.w + p1.w + p2.w + p3.w);
    *(float4*)(out + i) = o;
  }
}

extern "C" void kernel_launch(void* const* d_in, const int* in_sizes, int n_in,
                              void* d_out, int out_size, void* d_ws, size_t ws_size,
                              hipStream_t stream) {
  const float* X   = (const float*)d_in[0];
  const float* L   = (const float*)d_in[1];
  const float* Lu  = (const float*)d_in[2];
  const float* Ldn = (const float*)d_in[3];
  const float* Wp  = (const float*)d_in[4];
  const float* Wsm = (const float*)d_in[5];
  const float* Wu  = (const float*)d_in[6];
  const float* au1 = (const float*)d_in[7];
  const float* au2 = (const float*)d_in[8];
  const float* Wd  = (const float*)d_in[9];
  const float* ad1 = (const float*)d_in[10];
  const float* ad2 = (const float*)d_in[11];
  float* out = (float*)d_out;
  float* ws = (float*)d_ws;

  float* hmat = ws + OFF_HMAT;
  float* svec = ws + OFF_SVEC;
  float* hp   = ws + OFF_HP;
  float* gu   = ws + OFF_GU;
  float* gd   = ws + OFF_GD;
  _Float16* h0T = (_Float16*)(ws + OFF_H0T);
  u64* mask = (u64*)(ws + OFF_MASK);

  k_xw<<<dim3(NN / 128, 4, NDIM), 256, 0, stream>>>(X, Wp, Wsm, Wu, Wd, hmat, h0T);
  k_svec<<<dim3(NN / 4, 4, NDIM), 256, 0, stream>>>(hmat, au1, au2, ad1, ad2, svec);
  k_pack<<<2048, 256, 0, stream>>>(Lu, Ldn, mask);
  k_lgemm<<<dim3(NN / 64, 4, NDIM), 256, 0, stream>>>(L, h0T, hp);
  k_gat2<<<dim3(NN / 4, 2, NDIM), 256, 0, stream>>>(mask, hmat, svec, gu, gd);
  k_combine<<<1024, 256, 0, stream>>>(hmat, hp, gu, gd, out);
}

// Round 8
// 133.543 us; speedup vs baseline: 1.8227x; 1.0618x over previous
//
#include <hip/hip_runtime.h>
#include <hip/hip_bf16.h>

#define NN 4096
#define FD 128
#define NDIM 2
#define CAP 256

typedef unsigned long long u64;

// ---------- workspace layout (float offsets) ----------
// hmat [2][3][4096][128] fp32 : q=0 X@Ws (h_s), q=1 X@Wu, q=2 X@Wd
// svec [2][4][4096]           : v=0 s1u, 1 s2u, 2 s1d, 3 s2d
// hp   [2][4][4096][128] fp32 : split-K partials of L@h0
// gu,gd [2][4096][128]
// h0T  [2][128][4096] f16     : (X@Wp) transposed, f16 (B operand of L-GEMM)
// mask [2][2][4096][64] u64   : bit-packed adjacency (bit l of word w: col=(w>>2)*256+4l+(w&3))
#define OFF_HMAT 0
#define OFF_SVEC 3145728
#define OFF_HP   3178496
#define OFF_GU   7372800
#define OFF_GD   8421376
#define OFF_H0T  9469952
#define OFF_MASK 9994240

typedef _Float16 f16x8 __attribute__((ext_vector_type(8)));
typedef float f32x4 __attribute__((ext_vector_type(4)));
typedef float f32x4v __attribute__((ext_vector_type(4)));
typedef unsigned long long u64x2 __attribute__((ext_vector_type(2)));

union P4 { _Float16 h[4]; int2 i2; };

__device__ __forceinline__ float f4get(const float4& v, int j) {
    return j == 0 ? v.x : j == 1 ? v.y : j == 2 ? v.z : v.w;
}

// ---------------- K1: MFMA f16 GEMM  h = X @ W_p, tile 128x128, K=128 ----------------
__global__ __launch_bounds__(256) void k_xw(
    const float* __restrict__ X, const float* __restrict__ Wp,
    const float* __restrict__ Wsm, const float* __restrict__ Wu,
    const float* __restrict__ Wd, float* __restrict__ hmat,
    _Float16* __restrict__ h0T) {
  int d = blockIdx.z, p = blockIdx.y;
  int r0 = blockIdx.x * 128;
  const float* W = (p == 0 ? Wp : p == 1 ? Wsm : p == 2 ? Wu : Wd) + (size_t)d * FD * FD;
  const float* Xd = X + ((size_t)d * NN + r0) * FD;
  __shared__ int4 As4[2048];  // 32 KB
  __shared__ int4 Bs4[2048];  // 32 KB
  char* As = (char*)As4; char* Bs = (char*)Bs4;
  int t = threadIdx.x;

#pragma unroll 4
  for (int u = 0; u < 16; u++) {
    int id = t + u * 256;
    int row = id >> 5, k4 = (id & 31) * 4;
    float4 v = *(const float4*)(Xd + (size_t)row * FD + k4);
    P4 pk;
    pk.h[0] = (_Float16)v.x; pk.h[1] = (_Float16)v.y;
    pk.h[2] = (_Float16)v.z; pk.h[3] = (_Float16)v.w;
    int off = (row * 256 + k4 * 2) ^ ((row & 7) << 4);
    *(int2*)(As + off) = pk.i2;
  }
#pragma unroll 4
  for (int u = 0; u < 16; u++) {
    int id = t + u * 256;
    int k = id >> 5, n4 = (id & 31) * 4;
    float4 v = *(const float4*)(W + (size_t)k * FD + n4);
#pragma unroll
    for (int j = 0; j < 4; j++) {
      int n = n4 + j;
      int off = (n * 256 + k * 2) ^ ((n & 7) << 4);
      *(_Float16*)(Bs + off) = (_Float16)f4get(v, j);
    }
  }
  __syncthreads();

  int w = t >> 6, l = t & 63;
  int lr = l & 15, lkb = (l >> 4) * 16;
  f32x4 acc[2][8] = {};
#pragma unroll
  for (int kb = 0; kb < 4; kb++) {
    f16x8 a[2], b[8];
#pragma unroll
    for (int m = 0; m < 2; m++) {
      int row = w * 32 + m * 16 + lr;
      int off = (row * 256 + kb * 64 + lkb) ^ ((row & 7) << 4);
      a[m] = *(const f16x8*)(As + off);
    }
#pragma unroll
    for (int n = 0; n < 8; n++) {
      int rn = n * 16 + lr;
      int off = (rn * 256 + kb * 64 + lkb) ^ ((rn & 7) << 4);
      b[n] = *(const f16x8*)(Bs + off);
    }
#pragma unroll
    for (int m = 0; m < 2; m++)
#pragma unroll
      for (int n = 0; n < 8; n++)
        acc[m][n] = __builtin_amdgcn_mfma_f32_16x16x32_f16(a[m], b[n], acc[m][n], 0, 0, 0);
  }

  if (p == 0) {
    _Float16* hT = h0T + (size_t)d * FD * NN;
#pragma unroll
    for (int m = 0; m < 2; m++)
#pragma unroll
      for (int n = 0; n < 8; n++) {
        int col = n * 16 + lr;
        int grow = r0 + w * 32 + m * 16 + (l >> 4) * 4;
        P4 pk;
#pragma unroll
        for (int r = 0; r < 4; r++) pk.h[r] = (_Float16)acc[m][n][r];
        *(int2*)(hT + (size_t)col * NN + grow) = pk.i2;
      }
  } else {
    float* o = hmat + ((size_t)(d * 3 + p - 1) * NN + r0) * FD;
#pragma unroll
    for (int m = 0; m < 2; m++)
#pragma unroll
      for (int n = 0; n < 8; n++)
#pragma unroll
        for (int r = 0; r < 4; r++)
          o[(size_t)(w * 32 + m * 16 + (l >> 4) * 4 + r) * FD + n * 16 + lr] = acc[m][n][r];
  }
}

// ---------------- K1b: svec = h @ a ----------------
__global__ __launch_bounds__(256) void k_svec(
    const float* __restrict__ hmat, const float* __restrict__ au1,
    const float* __restrict__ au2, const float* __restrict__ ad1,
    const float* __restrict__ ad2, float* __restrict__ svec) {
  int v = blockIdx.y, d = blockIdx.z;
  int w = threadIdx.x >> 6, lane = threadIdx.x & 63;
  int i = blockIdx.x * 4 + w;
  const float* a = (v == 0 ? au1 : v == 1 ? au2 : v == 2 ? ad1 : ad2) + (size_t)d * FD;
  const float* h = hmat + ((size_t)(d * 3 + 1 + (v >> 1)) * NN + i) * FD;
  float x = h[lane] * a[lane] + h[64 + lane] * a[64 + lane];
#pragma unroll
  for (int o = 1; o < 64; o <<= 1) x += __shfl_xor(x, o);
  if (lane == 0) svec[(size_t)(d * 4 + v) * NN + i] = x;
}

// ---------------- K2: MFMA f16 GEMM  hp[d][ks] = L[d][:,slice] @ h0[slice,:]
//                  L staged with non-temporal loads (read-once stream) ------
__global__ __launch_bounds__(256) void k_lgemm(
    const float* __restrict__ L, const _Float16* __restrict__ h0T,
    float* __restrict__ hp) {
  int d = blockIdx.z, ks = blockIdx.y;
  int r0 = blockIdx.x * 64;
  const float* Lr = L + (size_t)d * NN * NN;
  const _Float16* hT = h0T + (size_t)d * FD * NN;
  __shared__ int4 As4[512];   //  8 KB
  __shared__ int4 Bs4[1024];  // 16 KB
  char* As = (char*)As4; char* Bs = (char*)Bs4;
  int t = threadIdx.x;
  int w = t >> 6, l = t & 63;
  int lr = l & 15, lkb = (l >> 4) * 16;
  f32x4 acc[8] = {};
  int kbeg = ks * 1024;
  for (int kk = kbeg; kk < kbeg + 1024; kk += 64) {
#pragma unroll
    for (int u = 0; u < 4; u++) {
      int id = t + u * 256;
      int row = id >> 4, k4 = (id & 15) * 4;
      f32x4v v = __builtin_nontemporal_load(
          (const f32x4v*)(Lr + (size_t)(r0 + row) * NN + kk) + (k4 >> 2));
      P4 pk;
      pk.h[0] = (_Float16)v[0]; pk.h[1] = (_Float16)v[1];
      pk.h[2] = (_Float16)v[2]; pk.h[3] = (_Float16)v[3];
      int off = (row * 128 + k4 * 2) ^ ((row & 7) << 4);
      *(int2*)(As + off) = pk.i2;
    }
#pragma unroll
    for (int u = 0; u < 4; u++) {
      int id = t + u * 256;
      int n = id >> 3, k8 = (id & 7) * 8;
      int4 v = *(const int4*)(hT + (size_t)n * NN + kk + k8);
      int off = (n * 128 + k8 * 2) ^ ((n & 7) << 4);
      *(int4*)(Bs + off) = v;
    }
    __syncthreads();
#pragma unroll
    for (int kb = 0; kb < 2; kb++) {
      int row = w * 16 + lr;
      int offA = (row * 128 + kb * 64 + lkb) ^ ((row & 7) << 4);
      f16x8 a = *(const f16x8*)(As + offA);
      f16x8 b[8];
#pragma unroll
      for (int n = 0; n < 8; n++) {
        int rn = n * 16 + lr;
        int off = (rn * 128 + kb * 64 + lkb) ^ ((rn & 7) << 4);
        b[n] = *(const f16x8*)(Bs + off);
      }
#pragma unroll
      for (int n = 0; n < 8; n++)
        acc[n] = __builtin_amdgcn_mfma_f32_16x16x32_f16(a, b[n], acc[n], 0, 0, 0);
    }
    __syncthreads();
  }
  float* o = hp + ((size_t)(d * 4 + ks) * NN + r0) * FD;
#pragma unroll
  for (int n = 0; n < 8; n++)
#pragma unroll
    for (int r = 0; r < 4; r++)
      o[(size_t)(w * 16 + (l >> 4) * 4 + r) * FD + n * 16 + lr] = acc[n][r];
}

// ---------------- K3a: bit-pack adjacency (nt streaming, 8 KB/wave) --------
// Quad = 4 pairs (2048 cols = half row). Word w of a row: bit l -> col
// (w>>2)*256 + 4*l + (w&3).
__global__ __launch_bounds__(256) void k_pack(
    const float* __restrict__ Lu, const float* __restrict__ Ldn,
    u64* __restrict__ mask) {
  int lane = threadIdx.x & 63;
  int wid = (blockIdx.x * 256 + threadIdx.x) >> 6;
  int nw = (gridDim.x * 256) >> 6;
  const int QTOT = 4 * NN * 2;  // 32768 half-rows
  for (int quad = wid; quad < QTOT; quad += nw) {
    int p = quad >> 13;           // plane: d = p>>1, a = p&1
    int rq = quad & 8191;
    int row = rq >> 1, half = rq & 1;
    const float* src = ((p & 1) ? Ldn : Lu) +
                       ((size_t)(p >> 1) * NN + row) * (size_t)NN + half * 2048;
    f32x4v v[8];
#pragma unroll
    for (int q = 0; q < 4; q++) {
      const f32x4v* s4 = (const f32x4v*)(src + q * 512);
      v[2 * q]     = __builtin_nontemporal_load(s4 + lane);
      v[2 * q + 1] = __builtin_nontemporal_load(s4 + 64 + lane);
    }
    u64* o = mask + ((size_t)p * NN + row) * 64 + half * 32;
#pragma unroll
    for (int q = 0; q < 4; q++) {
      u64 m0 = __ballot(v[2 * q][0] == 1.0f);
      u64 m1 = __ballot(v[2 * q][1] == 1.0f);
      u64 m2 = __ballot(v[2 * q][2] == 1.0f);
      u64 m3 = __ballot(v[2 * q][3] == 1.0f);
      u64 m4 = __ballot(v[2 * q + 1][0] == 1.0f);
      u64 m5 = __ballot(v[2 * q + 1][1] == 1.0f);
      u64 m6 = __ballot(v[2 * q + 1][2] == 1.0f);
      u64 m7 = __ballot(v[2 * q + 1][3] == 1.0f);
      if (lane == 0) {
        u64x2 a0 = {m0, m1}, a1 = {m2, m3}, a2 = {m4, m5}, a3 = {m6, m7};
        __builtin_nontemporal_store(a0, (u64x2*)(o + q * 8 + 0));
        __builtin_nontemporal_store(a1, (u64x2*)(o + q * 8 + 2));
        __builtin_nontemporal_store(a2, (u64x2*)(o + q * 8 + 4));
        __builtin_nontemporal_store(a3, (u64x2*)(o + q * 8 + 6));
      }
    }
  }
}

// ---------------- K3b: GAT from bitmask (wave per row) ----------------
__global__ __launch_bounds__(256) void k_gat2(
    const u64* __restrict__ mask, const float* __restrict__ hmat,
    const float* __restrict__ svec, float* __restrict__ gu,
    float* __restrict__ gd) {
  int d = blockIdx.z, a = blockIdx.y;
  int w = threadIdx.x >> 6, lane = threadIdx.x & 63;
  int i = blockIdx.x * 4 + w;
  const u64* mrow = mask + ((size_t)((d * 2 + a) * NN) + i) * 64;
  const float* h = hmat + (size_t)(d * 3 + 1 + a) * NN * FD;
  const float* s1 = svec + (size_t)(d * 4 + 2 * a) * NN;
  const float* s2 = svec + (size_t)(d * 4 + 2 * a + 1) * NN;
  float* g = (a ? gd : gu) + ((size_t)d * NN + i) * FD;

  __shared__ int ej[4][CAP];
  __shared__ float wt[4][CAP];

  // --- decode: lane l owns word l; prefix-sum counts; extract bits ---
  u64 m = mrow[lane];
  int c = __popcll(m);
  int pre = c;
#pragma unroll
  for (int o = 1; o < 64; o <<= 1) {
    int tv = __shfl_up(pre, o);
    if (lane >= o) pre += tv;
  }
  int cnt = __shfl(pre, 63);
  int base = pre - c;
  int colbase = (lane >> 2) * 256 + (lane & 3);
  while (m) {
    int b = __ffsll((unsigned long long)m) - 1;
    m &= m - 1;
    if (base < CAP) ej[w][base] = colbase + b * 4;
    base++;
  }
  cnt = min(cnt, CAP);

  // --- softmax over edges ---
  float s1i = s1[i];
  float mx = -1e30f;
  for (int e0 = 0; e0 < cnt; e0 += 64) {
    int e = e0 + lane;
    float sc = -1e30f;
    if (e < cnt) {
      int j = ej[w][e];
      float x = s1i + s2[j];
      sc = x > 0.0f ? x : 0.01f * x;
      wt[w][e] = sc;
    }
    mx = fmaxf(mx, sc);
  }
#pragma unroll
  for (int o = 1; o < 64; o <<= 1) mx = fmaxf(mx, __shfl_xor(mx, o));
  float sum = 0.0f;
  for (int e0 = 0; e0 < cnt; e0 += 64) {
    int e = e0 + lane;
    float pv = 0.0f;
    if (e < cnt) {
      pv = expf(wt[w][e] - mx);
      wt[w][e] = pv;
    }
    sum += pv;
  }
#pragma unroll
  for (int o = 1; o < 64; o <<= 1) sum += __shfl_xor(sum, o);
  float inv = (cnt > 0) ? 1.0f / sum : 0.0f;

  // --- gather: 4 edges (8 independent 256B loads) in flight ---
  float acc0 = 0.0f, acc1 = 0.0f;
  int e = 0;
  for (; e + 4 <= cnt; e += 4) {
    const float* r0 = h + (size_t)ej[w][e + 0] * FD;
    const float* r1 = h + (size_t)ej[w][e + 1] * FD;
    const float* r2 = h + (size_t)ej[w][e + 2] * FD;
    const float* r3 = h + (size_t)ej[w][e + 3] * FD;
    float w0 = wt[w][e + 0] * inv, w1 = wt[w][e + 1] * inv;
    float w2 = wt[w][e + 2] * inv, w3 = wt[w][e + 3] * inv;
    float a0 = r0[lane], b0 = r0[64 + lane];
    float a1 = r1[lane], b1 = r1[64 + lane];
    float a2 = r2[lane], b2 = r2[64 + lane];
    float a3 = r3[lane], b3 = r3[64 + lane];
    acc0 += w0 * a0 + w1 * a1 + w2 * a2 + w3 * a3;
    acc1 += w0 * b0 + w1 * b1 + w2 * b2 + w3 * b3;
  }
  for (; e < cnt; e++) {
    float wg = wt[w][e] * inv;
    const float* hr = h + (size_t)ej[w][e] * FD;
    acc0 += wg * hr[lane];
    acc1 += wg * hr[64 + lane];
  }
  g[lane] = acc0;
  g[64 + lane] = acc1;
}

// ---------------- K4: combine with tanh ----------------
__global__ __launch_bounds__(256) void k_combine(
    const float* __restrict__ hmat, const float* __restrict__ hp,
    const float* __restrict__ gu, const float* __restrict__ gd,
    float* __restrict__ out) {
  const size_t tot4 = (size_t)NDIM * NN * FD / 4;
  for (size_t i4 = (size_t)blockIdx.x * blockDim.x + threadIdx.x; i4 < tot4;
       i4 += (size_t)gridDim.x * blockDim.x) {
    size_t i = i4 * 4;
    int d = (int)(i >> 19);
    size_t rem = i & 524287;
    float4 hs = *(const float4*)(hmat + ((size_t)(d * 3) << 19) + rem);
    float4 p0 = *(const float4*)(hp + ((size_t)(d * 4 + 0) << 19) + rem);
    float4 p1 = *(const float4*)(hp + ((size_t)(d * 4 + 1) << 19) + rem);
    float4 p2 = *(const float4*)(hp + ((size_t)(d * 4 + 2) << 19) + rem);
    float4 p3 = *(const float4*)(hp + ((size_t)(d * 4 + 3) << 19) + rem);
    float4 u = *(const float4*)(gu + ((size_t)d << 19) + rem);
    float4 dd = *(const float4*)(gd + ((size_t)d << 19) + rem);
    float4 o;
    o.x = tanhf(hs.x) + tanhf(u.x) + tanhf(dd.x) + tanhf(p0.x + p1.x + p2.x + p3.x);
    o.y = tanhf(hs.y) + tanhf(u.y) + tanhf(dd.y) + tanhf(p0.y + p1.y + p2.y + p3.y);
    o.z = tanhf(hs.z) + tanhf(u.z) + tanhf(dd.z) + tanhf(p0.z + p1.z + p2.z + p3.z);
    o.w = tanhf(hs.w) + tanhf(u.w) + tanhf(dd.w) + tanhf(p0.w + p1.w + p2.w + p3.w);
    *(float4*)(out + i) = o;
  }
}

extern "C" void kernel_launch(void* const* d_in, const int* in_sizes, int n_in,
                              void* d_out, int out_size, void* d_ws, size_t ws_size,
                              hipStream_t stream) {
  const float* X   = (const float*)d_in[0];
  const float* L   = (const float*)d_in[1];
  const float* Lu  = (const float*)d_in[2];
  const float* Ldn = (const float*)d_in[3];
  const float* Wp  = (const float*)d_in[4];
  const float* Wsm = (const float*)d_in[5];
  const float* Wu  = (const float*)d_in[6];
  const float* au1 = (const float*)d_in[7];
  const float* au2 = (const float*)d_in[8];
  const float* Wd  = (const float*)d_in[9];
  const float* ad1 = (const float*)d_in[10];
  const float* ad2 = (const float*)d_in[11];
  float* out = (float*)d_out;
  float* ws = (float*)d_ws;

  float* hmat = ws + OFF_HMAT;
  float* svec = ws + OFF_SVEC;
  float* hp   = ws + OFF_HP;
  float* gu   = ws + OFF_GU;
  float* gd   = ws + OFF_GD;
  _Float16* h0T = (_Float16*)(ws + OFF_H0T);
  u64* mask = (u64*)(ws + OFF_MASK);

  k_xw<<<dim3(NN / 128, 4, NDIM), 256, 0, stream>>>(X, Wp, Wsm, Wu, Wd, hmat, h0T);
  k_svec<<<dim3(NN / 4, 4, NDIM), 256, 0, stream>>>(hmat, au1, au2, ad1, ad2, svec);
  k_pack<<<2048, 256, 0, stream>>>(Lu, Ldn, mask);
  k_lgemm<<<dim3(NN / 64, 4, NDIM), 256, 0, stream>>>(L, h0T, hp);
  k_gat2<<<dim3(NN / 4, 2, NDIM), 256, 0, stream>>>(mask, hmat, svec, gu, gd);
  k_combine<<<1024, 256, 0, stream>>>(hmat, hp, gu, gd, out);
}

// Round 9
// 124.534 us; speedup vs baseline: 1.9546x; 1.0723x over previous
//
#include <hip/hip_runtime.h>
#include <hip/hip_bf16.h>

#define NN 4096
#define FD 128
#define NDIM 2
#define CAP 256

typedef unsigned long long u64;

// ---------- workspace layout (float offsets) ----------
// hmat [2][3][4096][128] fp32 : q=0 X@Ws (h_s), q=1 X@Wu, q=2 X@Wd
// svec [2][4][4096]           : v=0 s1u, 1 s2u, 2 s1d, 3 s2d
// hp   [2][4][4096][128] fp32 : split-K partials of L@h0
// h0T  [2][128][4096] f16     : (X@Wp) transposed, f16 (B operand of L-GEMM)
// mask [2][2][4096][64] u64   : bit-packed adjacency (bit l of word w: col=(w>>2)*256+4l+(w&3))
#define OFF_HMAT 0
#define OFF_SVEC 3145728
#define OFF_HP   3178496
#define OFF_H0T  7372800
#define OFF_MASK 7897088

typedef _Float16 f16x8 __attribute__((ext_vector_type(8)));
typedef float f32x4 __attribute__((ext_vector_type(4)));
typedef float f32x4v __attribute__((ext_vector_type(4)));
typedef unsigned long long u64x2 __attribute__((ext_vector_type(2)));

union P4 { _Float16 h[4]; int2 i2; };

__device__ __forceinline__ float f4get(const float4& v, int j) {
    return j == 0 ? v.x : j == 1 ? v.y : j == 2 ? v.z : v.w;
}

// ---------------- K1: MFMA f16 GEMM  h = X @ W_p, tile 128x128, K=128 ----------------
__global__ __launch_bounds__(256) void k_xw(
    const float* __restrict__ X, const float* __restrict__ Wp,
    const float* __restrict__ Wsm, const float* __restrict__ Wu,
    const float* __restrict__ Wd, float* __restrict__ hmat,
    _Float16* __restrict__ h0T) {
  int d = blockIdx.z, p = blockIdx.y;
  int r0 = blockIdx.x * 128;
  const float* W = (p == 0 ? Wp : p == 1 ? Wsm : p == 2 ? Wu : Wd) + (size_t)d * FD * FD;
  const float* Xd = X + ((size_t)d * NN + r0) * FD;
  __shared__ int4 As4[2048];  // 32 KB
  __shared__ int4 Bs4[2048];  // 32 KB
  char* As = (char*)As4; char* Bs = (char*)Bs4;
  int t = threadIdx.x;

#pragma unroll 4
  for (int u = 0; u < 16; u++) {
    int id = t + u * 256;
    int row = id >> 5, k4 = (id & 31) * 4;
    float4 v = *(const float4*)(Xd + (size_t)row * FD + k4);
    P4 pk;
    pk.h[0] = (_Float16)v.x; pk.h[1] = (_Float16)v.y;
    pk.h[2] = (_Float16)v.z; pk.h[3] = (_Float16)v.w;
    int off = (row * 256 + k4 * 2) ^ ((row & 7) << 4);
    *(int2*)(As + off) = pk.i2;
  }
#pragma unroll 4
  for (int u = 0; u < 16; u++) {
    int id = t + u * 256;
    int k = id >> 5, n4 = (id & 31) * 4;
    float4 v = *(const float4*)(W + (size_t)k * FD + n4);
#pragma unroll
    for (int j = 0; j < 4; j++) {
      int n = n4 + j;
      int off = (n * 256 + k * 2) ^ ((n & 7) << 4);
      *(_Float16*)(Bs + off) = (_Float16)f4get(v, j);
    }
  }
  __syncthreads();

  int w = t >> 6, l = t & 63;
  int lr = l & 15, lkb = (l >> 4) * 16;
  f32x4 acc[2][8] = {};
#pragma unroll
  for (int kb = 0; kb < 4; kb++) {
    f16x8 a[2], b[8];
#pragma unroll
    for (int m = 0; m < 2; m++) {
      int row = w * 32 + m * 16 + lr;
      int off = (row * 256 + kb * 64 + lkb) ^ ((row & 7) << 4);
      a[m] = *(const f16x8*)(As + off);
    }
#pragma unroll
    for (int n = 0; n < 8; n++) {
      int rn = n * 16 + lr;
      int off = (rn * 256 + kb * 64 + lkb) ^ ((rn & 7) << 4);
      b[n] = *(const f16x8*)(Bs + off);
    }
#pragma unroll
    for (int m = 0; m < 2; m++)
#pragma unroll
      for (int n = 0; n < 8; n++)
        acc[m][n] = __builtin_amdgcn_mfma_f32_16x16x32_f16(a[m], b[n], acc[m][n], 0, 0, 0);
  }

  if (p == 0) {
    _Float16* hT = h0T + (size_t)d * FD * NN;
#pragma unroll
    for (int m = 0; m < 2; m++)
#pragma unroll
      for (int n = 0; n < 8; n++) {
        int col = n * 16 + lr;
        int grow = r0 + w * 32 + m * 16 + (l >> 4) * 4;
        P4 pk;
#pragma unroll
        for (int r = 0; r < 4; r++) pk.h[r] = (_Float16)acc[m][n][r];
        *(int2*)(hT + (size_t)col * NN + grow) = pk.i2;
      }
  } else {
    float* o = hmat + ((size_t)(d * 3 + p - 1) * NN + r0) * FD;
#pragma unroll
    for (int m = 0; m < 2; m++)
#pragma unroll
      for (int n = 0; n < 8; n++)
#pragma unroll
        for (int r = 0; r < 4; r++)
          o[(size_t)(w * 32 + m * 16 + (l >> 4) * 4 + r) * FD + n * 16 + lr] = acc[m][n][r];
  }
}

// ---------------- K1b: svec = h @ a ----------------
__global__ __launch_bounds__(256) void k_svec(
    const float* __restrict__ hmat, const float* __restrict__ au1,
    const float* __restrict__ au2, const float* __restrict__ ad1,
    const float* __restrict__ ad2, float* __restrict__ svec) {
  int v = blockIdx.y, d = blockIdx.z;
  int w = threadIdx.x >> 6, lane = threadIdx.x & 63;
  int i = blockIdx.x * 4 + w;
  const float* a = (v == 0 ? au1 : v == 1 ? au2 : v == 2 ? ad1 : ad2) + (size_t)d * FD;
  const float* h = hmat + ((size_t)(d * 3 + 1 + (v >> 1)) * NN + i) * FD;
  float x = h[lane] * a[lane] + h[64 + lane] * a[64 + lane];
#pragma unroll
  for (int o = 1; o < 64; o <<= 1) x += __shfl_xor(x, o);
  if (lane == 0) svec[(size_t)(d * 4 + v) * NN + i] = x;
}

// ---------------- K2: fused lgemm + pack (block specialization) -------------
// blocks [0,512)    : hp[d][ks] = L[d][:,slice] @ h0[slice,:]  (BM=64, nt L)
// blocks [512,8704) : bit-pack adjacency; wave = one 8 KB half-row, nt
__global__ __launch_bounds__(256) void k_mega(
    const float* __restrict__ L, const _Float16* __restrict__ h0T,
    float* __restrict__ hp,
    const float* __restrict__ Lu, const float* __restrict__ Ldn,
    u64* __restrict__ mask) {
  __shared__ int4 sm4[1536];  // 24 KB (lgemm path only)
  int t = threadIdx.x, w = t >> 6, lane = t & 63;

  if (blockIdx.x < 512) {
    // ---------------- lgemm path ----------------
    int b = blockIdx.x;
    int r0 = (b & 63) * 64, ks = (b >> 6) & 3, d = b >> 8;
    const float* Lr = L + (size_t)d * NN * NN;
    const _Float16* hT = h0T + (size_t)d * FD * NN;
    char* As = (char*)sm4;            //  8 KB
    char* Bs = (char*)(sm4 + 512);    // 16 KB
    int lr = lane & 15, lkb = (lane >> 4) * 16;
    f32x4 acc[8] = {};
    int kbeg = ks * 1024;
    for (int kk = kbeg; kk < kbeg + 1024; kk += 64) {
#pragma unroll
      for (int u = 0; u < 4; u++) {
        int id = t + u * 256;
        int row = id >> 4, k4 = (id & 15) * 4;
        f32x4v v = __builtin_nontemporal_load(
            (const f32x4v*)(Lr + (size_t)(r0 + row) * NN + kk) + (k4 >> 2));
        P4 pk;
        pk.h[0] = (_Float16)v[0]; pk.h[1] = (_Float16)v[1];
        pk.h[2] = (_Float16)v[2]; pk.h[3] = (_Float16)v[3];
        int off = (row * 128 + k4 * 2) ^ ((row & 7) << 4);
        *(int2*)(As + off) = pk.i2;
      }
#pragma unroll
      for (int u = 0; u < 4; u++) {
        int id = t + u * 256;
        int n = id >> 3, k8 = (id & 7) * 8;
        int4 v = *(const int4*)(hT + (size_t)n * NN + kk + k8);
        int off = (n * 128 + k8 * 2) ^ ((n & 7) << 4);
        *(int4*)(Bs + off) = v;
      }
      __syncthreads();
#pragma unroll
      for (int kb = 0; kb < 2; kb++) {
        int row = w * 16 + lr;
        int offA = (row * 128 + kb * 64 + lkb) ^ ((row & 7) << 4);
        f16x8 a = *(const f16x8*)(As + offA);
        f16x8 bb[8];
#pragma unroll
        for (int n = 0; n < 8; n++) {
          int rn = n * 16 + lr;
          int off = (rn * 128 + kb * 64 + lkb) ^ ((rn & 7) << 4);
          bb[n] = *(const f16x8*)(Bs + off);
        }
#pragma unroll
        for (int n = 0; n < 8; n++)
          acc[n] = __builtin_amdgcn_mfma_f32_16x16x32_f16(a, bb[n], acc[n], 0, 0, 0);
      }
      __syncthreads();
    }
    float* o = hp + ((size_t)(d * 4 + ks) * NN + r0) * FD;
#pragma unroll
    for (int n = 0; n < 8; n++)
#pragma unroll
      for (int r = 0; r < 4; r++)
        o[(size_t)(w * 16 + (lane >> 4) * 4 + r) * FD + n * 16 + lr] = acc[n][r];
    return;
  }

  // ---------------- pack path: wave = one half-row (2048 cols, 8 KB) -------
  int hr = (blockIdx.x - 512) * 4 + w;       // [0, 32768)
  int p = hr >> 13;                          // plane: d = p>>1, a = p&1
  int rq = hr & 8191;
  int row = rq >> 1, half = rq & 1;
  const float* src = ((p & 1) ? Ldn : Lu) +
                     ((size_t)(p >> 1) * NN + row) * (size_t)NN + half * 2048;
  f32x4v v[8];
#pragma unroll
  for (int q = 0; q < 4; q++) {
    const f32x4v* s4 = (const f32x4v*)(src + q * 512);
    v[2 * q]     = __builtin_nontemporal_load(s4 + lane);
    v[2 * q + 1] = __builtin_nontemporal_load(s4 + 64 + lane);
  }
  u64* o = mask + ((size_t)p * NN + row) * 64 + half * 32;
#pragma unroll
  for (int q = 0; q < 4; q++) {
    u64 m0 = __ballot(v[2 * q][0] == 1.0f);
    u64 m1 = __ballot(v[2 * q][1] == 1.0f);
    u64 m2 = __ballot(v[2 * q][2] == 1.0f);
    u64 m3 = __ballot(v[2 * q][3] == 1.0f);
    u64 m4 = __ballot(v[2 * q + 1][0] == 1.0f);
    u64 m5 = __ballot(v[2 * q + 1][1] == 1.0f);
    u64 m6 = __ballot(v[2 * q + 1][2] == 1.0f);
    u64 m7 = __ballot(v[2 * q + 1][3] == 1.0f);
    if (lane == 0) {
      u64x2 a0 = {m0, m1}, a1 = {m2, m3}, a2 = {m4, m5}, a3 = {m6, m7};
      __builtin_nontemporal_store(a0, (u64x2*)(o + q * 8 + 0));
      __builtin_nontemporal_store(a1, (u64x2*)(o + q * 8 + 2));
      __builtin_nontemporal_store(a2, (u64x2*)(o + q * 8 + 4));
      __builtin_nontemporal_store(a3, (u64x2*)(o + q * 8 + 6));
    }
  }
}

// ---------------- K3: GAT (both adjacencies) + combine, wave per row -------
__global__ __launch_bounds__(256) void k_gatc(
    const u64* __restrict__ mask, const float* __restrict__ hmat,
    const float* __restrict__ svec, const float* __restrict__ hp,
    float* __restrict__ out) {
  int d = blockIdx.y;
  int w = threadIdx.x >> 6, lane = threadIdx.x & 63;
  int i = blockIdx.x * 4 + w;

  __shared__ int ej[4][2][CAP];
  __shared__ float wt[4][2][CAP];

  float ga[2][2];  // [a][half]
#pragma unroll
  for (int a = 0; a < 2; a++) {
    const u64* mrow = mask + ((size_t)((d * 2 + a) * NN) + i) * 64;
    const float* h = hmat + (size_t)(d * 3 + 1 + a) * NN * FD;
    const float* s1 = svec + (size_t)(d * 4 + 2 * a) * NN;
    const float* s2 = svec + (size_t)(d * 4 + 2 * a + 1) * NN;

    // --- decode: lane l owns word l; prefix-sum counts; extract bits ---
    u64 m = mrow[lane];
    int c = __popcll(m);
    int pre = c;
#pragma unroll
    for (int o = 1; o < 64; o <<= 1) {
      int tv = __shfl_up(pre, o);
      if (lane >= o) pre += tv;
    }
    int cnt = __shfl(pre, 63);
    int base = pre - c;
    int colbase = (lane >> 2) * 256 + (lane & 3);
    while (m) {
      int b = __ffsll((unsigned long long)m) - 1;
      m &= m - 1;
      if (base < CAP) ej[w][a][base] = colbase + b * 4;
      base++;
    }
    cnt = min(cnt, CAP);

    // --- softmax over edges ---
    float s1i = s1[i];
    float mx = -1e30f;
    for (int e0 = 0; e0 < cnt; e0 += 64) {
      int e = e0 + lane;
      float sc = -1e30f;
      if (e < cnt) {
        int j = ej[w][a][e];
        float x = s1i + s2[j];
        sc = x > 0.0f ? x : 0.01f * x;
        wt[w][a][e] = sc;
      }
      mx = fmaxf(mx, sc);
    }
#pragma unroll
    for (int o = 1; o < 64; o <<= 1) mx = fmaxf(mx, __shfl_xor(mx, o));
    float sum = 0.0f;
    for (int e0 = 0; e0 < cnt; e0 += 64) {
      int e = e0 + lane;
      float pv = 0.0f;
      if (e < cnt) {
        pv = expf(wt[w][a][e] - mx);
        wt[w][a][e] = pv;
      }
      sum += pv;
    }
#pragma unroll
    for (int o = 1; o < 64; o <<= 1) sum += __shfl_xor(sum, o);
    float inv = (cnt > 0) ? 1.0f / sum : 0.0f;

    // --- gather ---
    float acc0 = 0.0f, acc1 = 0.0f;
    int e = 0;
    for (; e + 4 <= cnt; e += 4) {
      const float* r0 = h + (size_t)ej[w][a][e + 0] * FD;
      const float* r1 = h + (size_t)ej[w][a][e + 1] * FD;
      const float* r2 = h + (size_t)ej[w][a][e + 2] * FD;
      const float* r3 = h + (size_t)ej[w][a][e + 3] * FD;
      float w0 = wt[w][a][e + 0] * inv, w1 = wt[w][a][e + 1] * inv;
      float w2 = wt[w][a][e + 2] * inv, w3 = wt[w][a][e + 3] * inv;
      float a0 = r0[lane], b0 = r0[64 + lane];
      float a1 = r1[lane], b1 = r1[64 + lane];
      float a2 = r2[lane], b2 = r2[64 + lane];
      float a3 = r3[lane], b3 = r3[64 + lane];
      acc0 += w0 * a0 + w1 * a1 + w2 * a2 + w3 * a3;
      acc1 += w0 * b0 + w1 * b1 + w2 * b2 + w3 * b3;
    }
    for (; e < cnt; e++) {
      float wg = wt[w][a][e] * inv;
      const float* hr = h + (size_t)ej[w][a][e] * FD;
      acc0 += wg * hr[lane];
      acc1 += wg * hr[64 + lane];
    }
    ga[a][0] = acc0;
    ga[a][1] = acc1;
  }

  // --- combine: out = tanh(hs) + tanh(gu) + tanh(gd) + tanh(sum hp) ---
  const float* hs = hmat + ((size_t)(d * 3) * NN + i) * FD;
  const float* h0 = hp + ((size_t)(d * 4 + 0) * NN + i) * FD;
  const float* h1 = hp + ((size_t)(d * 4 + 1) * NN + i) * FD;
  const float* h2 = hp + ((size_t)(d * 4 + 2) * NN + i) * FD;
  const float* h3 = hp + ((size_t)(d * 4 + 3) * NN + i) * FD;
  float* o = out + ((size_t)d * NN + i) * FD;
#pragma unroll
  for (int hf = 0; hf < 2; hf++) {
    int col = hf * 64 + lane;
    float ps = h0[col] + h1[col] + h2[col] + h3[col];
    o[col] = tanhf(hs[col]) + tanhf(ga[0][hf]) + tanhf(ga[1][hf]) + tanhf(ps);
  }
}

extern "C" void kernel_launch(void* const* d_in, const int* in_sizes, int n_in,
                              void* d_out, int out_size, void* d_ws, size_t ws_size,
                              hipStream_t stream) {
  const float* X   = (const float*)d_in[0];
  const float* L   = (const float*)d_in[1];
  const float* Lu  = (const float*)d_in[2];
  const float* Ldn = (const float*)d_in[3];
  const float* Wp  = (const float*)d_in[4];
  const float* Wsm = (const float*)d_in[5];
  const float* Wu  = (const float*)d_in[6];
  const float* au1 = (const float*)d_in[7];
  const float* au2 = (const float*)d_in[8];
  const float* Wd  = (const float*)d_in[9];
  const float* ad1 = (const float*)d_in[10];
  const float* ad2 = (const float*)d_in[11];
  float* out = (float*)d_out;
  float* ws = (float*)d_ws;

  float* hmat = ws + OFF_HMAT;
  float* svec = ws + OFF_SVEC;
  float* hp   = ws + OFF_HP;
  _Float16* h0T = (_Float16*)(ws + OFF_H0T);
  u64* mask = (u64*)(ws + OFF_MASK);

  k_xw<<<dim3(NN / 128, 4, NDIM), 256, 0, stream>>>(X, Wp, Wsm, Wu, Wd, hmat, h0T);
  k_svec<<<dim3(NN / 4, 4, NDIM), 256, 0, stream>>>(hmat, au1, au2, ad1, ad2, svec);
  k_mega<<<dim3(512 + 8192, 1, 1), 256, 0, stream>>>(L, h0T, hp, Lu, Ldn, mask);
  k_gatc<<<dim3(NN / 4, NDIM, 1), 256, 0, stream>>>(mask, hmat, svec, hp, out);
}